// Round 1
// baseline (223.124 us; speedup 1.0000x reference)
//
#include <hip/hip_runtime.h>

// conv_layer: out[b,v,o] = sum_{j<7,c<64} x[b, neigh[v*7+j], c] * W[o, j*64+c] + bias[o]
// B=2, V=163842, C_IN=C_OUT=64, K=448. Strategy: bf16 MFMA gather-GEMM.

constexpr int V_ICO   = 163842;
constexpr int C       = 64;
constexpr int KTOT    = 448;              // 7*64
constexpr int M_TOTAL = 2 * V_ICO;        // 327684
constexpr int X_ELEMS = M_TOTAL * C;      // 20,971,776
constexpr int W_ELEMS = C * KTOT;         // 28,672
constexpr int XCH     = X_ELEMS / 8;      // 16B chunks of x
constexpr int WCH     = W_ELEMS / 8;      // 3584

typedef __attribute__((ext_vector_type(4))) float          f32x4;
typedef __attribute__((ext_vector_type(4))) unsigned int   u32x4;
typedef __attribute__((ext_vector_type(8))) unsigned short u16x8;
typedef __attribute__((ext_vector_type(8))) __bf16         bf16x8;

union BF8 { u32x4 q; u16x8 u; bf16x8 v; };

static __device__ __forceinline__ unsigned short f2bf(float f) {
  unsigned int t = __float_as_uint(f);
  t += 0x7FFFu + ((t >> 16) & 1u);   // round-to-nearest-even
  return (unsigned short)(t >> 16);
}

static __device__ __forceinline__ u32x4 cvt8(f32x4 a, f32x4 b) {
  BF8 r;
  r.u[0] = f2bf(a[0]); r.u[1] = f2bf(a[1]); r.u[2] = f2bf(a[2]); r.u[3] = f2bf(a[3]);
  r.u[4] = f2bf(b[0]); r.u[5] = f2bf(b[1]); r.u[6] = f2bf(b[2]); r.u[7] = f2bf(b[3]);
  return r.q;
}

// Convert x (and W, appended) fp32 -> bf16 into workspace.
__global__ __launch_bounds__(256)
void cvt_x_w(const float* __restrict__ x, const float* __restrict__ W,
             u32x4* __restrict__ xbf, u32x4* __restrict__ wbf) {
  const int stride = gridDim.x * blockDim.x;
  for (int i = blockIdx.x * blockDim.x + threadIdx.x; i < XCH + WCH; i += stride) {
    const f32x4* src;
    u32x4* dst;
    if (i < XCH) {
      src = reinterpret_cast<const f32x4*>(x) + 2 * (size_t)i;
      dst = xbf + i;
    } else {
      const int k = i - XCH;
      src = reinterpret_cast<const f32x4*>(W) + 2 * (size_t)k;
      dst = wbf + k;
    }
    f32x4 f0 = src[0], f1 = src[1];
    *dst = cvt8(f0, f1);
  }
}

__global__ __launch_bounds__(256)
void cvt_w_only(const float* __restrict__ W, u32x4* __restrict__ wbf) {
  const int i = blockIdx.x * blockDim.x + threadIdx.x;
  if (i < WCH) {
    const f32x4* src = reinterpret_cast<const f32x4*>(W) + 2 * (size_t)i;
    f32x4 f0 = src[0], f1 = src[1];
    wbf[i] = cvt8(f0, f1);
  }
}

// Main gather-GEMM. Block = 512 threads = 8 waves; each wave owns 16 output rows,
// all 64 output channels (4x mfma_f32_16x16x32_bf16 accumulators over 14 k-chunks).
// XBF: x already bf16 in ws.  WPRE: W already bf16 in ws.
template <int XBF, int WPRE>
__global__ __launch_bounds__(512, 4)
void gather_mm(const float* __restrict__ x32, const unsigned short* __restrict__ x16,
               const int* __restrict__ neigh,
               const float* __restrict__ W32, const unsigned short* __restrict__ W16,
               const float* __restrict__ bias, float* __restrict__ out) {
  // W in LDS: [o][k], row-padded to 456 elems (912 B stride, +16B mod 128 -> ~2-way banks)
  __shared__ __align__(16) unsigned short Wlds[64][456];

  const int tid = threadIdx.x;
  for (int i = tid; i < 64 * 56; i += 512) {
    const int row = i / 56, ch = i - row * 56;
    u32x4 val;
    if constexpr (WPRE) {
      val = reinterpret_cast<const u32x4*>(W16)[i];           // chunk i == row*56+ch
    } else {
      const f32x4* p = reinterpret_cast<const f32x4*>(W32 + row * 448 + ch * 8);
      val = cvt8(p[0], p[1]);
    }
    *reinterpret_cast<u32x4*>(&Wlds[row][ch * 8]) = val;
  }
  __syncthreads();

  const int w    = tid >> 6;
  const int lane = tid & 63;
  const int r    = lane & 15;   // A row within tile / output channel low bits
  const int g    = lane >> 4;   // k-group 0..3
  const int m0   = blockIdx.x * 128 + w * 16;
  if (m0 >= M_TOTAL) return;    // after the one barrier: legal

  int mA = m0 + r;
  if (mA > M_TOTAL - 1) mA = M_TOTAL - 1;          // clamp for safe index loads
  const int bA = (mA >= V_ICO) ? 1 : 0;
  const int vA = mA - bA * V_ICO;

  int nofs[7];
#pragma unroll
  for (int j = 0; j < 7; ++j) nofs[j] = neigh[vA * 7 + j];

  const unsigned short* xb16 = nullptr;
  const float* xb32 = nullptr;
  if constexpr (XBF) xb16 = x16 + (size_t)bA * V_ICO * 64;
  else               xb32 = x32 + (size_t)bA * V_ICO * 64;

  const f32x4 zero = {0.f, 0.f, 0.f, 0.f};
  f32x4 acc[4] = {zero, zero, zero, zero};

  // K loop: 14 chunks of 32. A-frag: lane reads 8 contiguous channels of one
  // gathered neighbor row (k = kc*32 + g*8 + i). Fully unrolled -> compile-time
  // nofs[] indices, many gathers in flight.
#pragma unroll
  for (int kc = 0; kc < 14; ++kc) {
    const int j  = kc >> 1;
    const int c0 = ((kc & 1) << 5) | (g << 3);
    BF8 a;
    if constexpr (XBF) {
      a.q = *reinterpret_cast<const u32x4*>(xb16 + (size_t)nofs[j] * 64 + c0);
    } else {
      const f32x4* p = reinterpret_cast<const f32x4*>(xb32 + (size_t)nofs[j] * 64 + c0);
      a.q = cvt8(p[0], p[1]);
    }
    const int kb = kc * 32 + (g << 3);
    const bf16x8* pb0 = reinterpret_cast<const bf16x8*>(&Wlds[r][kb]);
    const bf16x8* pb1 = reinterpret_cast<const bf16x8*>(&Wlds[16 + r][kb]);
    const bf16x8* pb2 = reinterpret_cast<const bf16x8*>(&Wlds[32 + r][kb]);
    const bf16x8* pb3 = reinterpret_cast<const bf16x8*>(&Wlds[48 + r][kb]);
    acc[0] = __builtin_amdgcn_mfma_f32_16x16x32_bf16(a.v, *pb0, acc[0], 0, 0, 0);
    acc[1] = __builtin_amdgcn_mfma_f32_16x16x32_bf16(a.v, *pb1, acc[1], 0, 0, 0);
    acc[2] = __builtin_amdgcn_mfma_f32_16x16x32_bf16(a.v, *pb2, acc[2], 0, 0, 0);
    acc[3] = __builtin_amdgcn_mfma_f32_16x16x32_bf16(a.v, *pb3, acc[3], 0, 0, 0);
  }

  // C/D layout (m89-verified): col = lane&15 (=r -> channel), row = g*4 + reg.
#pragma unroll
  for (int nt = 0; nt < 4; ++nt) {
    const int o = (nt << 4) + r;
    const float bv = bias[o];
#pragma unroll
    for (int q2 = 0; q2 < 4; ++q2) {
      const int mS = m0 + (g << 2) + q2;
      if (mS < M_TOTAL) out[(size_t)mS * 64 + o] = acc[nt][q2] + bv;
    }
  }
}

extern "C" void kernel_launch(void* const* d_in, const int* in_sizes, int n_in,
                              void* d_out, int out_size, void* d_ws, size_t ws_size,
                              hipStream_t stream) {
  const float* x    = (const float*)d_in[0];
  const int*   nbr  = (const int*)d_in[1];
  const float* W    = (const float*)d_in[2];
  const float* bias = (const float*)d_in[3];
  float* out = (float*)d_out;

  const size_t xbf_bytes = (size_t)X_ELEMS * 2;   // 41,943,552
  const size_t wbf_bytes = (size_t)W_ELEMS * 2;   // 57,344
  const int grid_main = (M_TOTAL + 127) / 128;    // 2561

  if (ws_size >= xbf_bytes + wbf_bytes) {
    u32x4* xbf = (u32x4*)d_ws;
    u32x4* wbf = (u32x4*)((char*)d_ws + xbf_bytes);
    hipLaunchKernelGGL(cvt_x_w, dim3(2048), dim3(256), 0, stream, x, W, xbf, wbf);
    hipLaunchKernelGGL((gather_mm<1, 1>), dim3(grid_main), dim3(512), 0, stream,
                       x, (const unsigned short*)xbf, nbr,
                       W, (const unsigned short*)wbf, bias, out);
  } else if (ws_size >= wbf_bytes) {
    u32x4* wbf = (u32x4*)d_ws;
    hipLaunchKernelGGL(cvt_w_only, dim3((WCH + 255) / 256), dim3(256), 0, stream, W, wbf);
    hipLaunchKernelGGL((gather_mm<0, 1>), dim3(grid_main), dim3(512), 0, stream,
                       x, nullptr, nbr, W, (const unsigned short*)wbf, bias, out);
  } else {
    hipLaunchKernelGGL((gather_mm<0, 0>), dim3(grid_main), dim3(512), 0, stream,
                       x, nullptr, nbr, W, nullptr, bias, out);
  }
}

// Round 2
// 207.589 us; speedup vs baseline: 1.0748x; 1.0748x over previous
//
#include <hip/hip_runtime.h>

// conv_layer: out[b,v,o] = sum_{j<7,c<64} x[b, neigh[v*7+j], c] * W[o, j*64+c] + bias[o]
// B=2, V=163842, C_IN=C_OUT=64, K=448. bf16 MFMA gather-GEMM.
// R2: 1024-thread blocks (32 waves/CU), explicit depth-2 gather pipeline, nt stores.

constexpr int V_ICO   = 163842;
constexpr int M_TOTAL = 2 * V_ICO;        // 327684
constexpr int X_ELEMS = M_TOTAL * 64;     // 20,971,776
constexpr int W_ELEMS = 64 * 448;         // 28,672
constexpr int XCH     = X_ELEMS / 8;      // 16B bf16 chunks of x
constexpr int WCH     = W_ELEMS / 8;      // 3584

typedef __attribute__((ext_vector_type(4))) float          f32x4;
typedef __attribute__((ext_vector_type(4))) unsigned int   u32x4;
typedef __attribute__((ext_vector_type(8))) unsigned short u16x8;
typedef __attribute__((ext_vector_type(8))) __bf16         bf16x8;

union BF8 { u32x4 q; u16x8 u; bf16x8 v; };

static __device__ __forceinline__ unsigned short f2bf(float f) {
  unsigned int t = __float_as_uint(f);
  t += 0x7FFFu + ((t >> 16) & 1u);   // round-to-nearest-even
  return (unsigned short)(t >> 16);
}

static __device__ __forceinline__ u32x4 cvt8(f32x4 a, f32x4 b) {
  BF8 r;
  r.u[0] = f2bf(a[0]); r.u[1] = f2bf(a[1]); r.u[2] = f2bf(a[2]); r.u[3] = f2bf(a[3]);
  r.u[4] = f2bf(b[0]); r.u[5] = f2bf(b[1]); r.u[6] = f2bf(b[2]); r.u[7] = f2bf(b[3]);
  return r.q;
}

// fp32 -> bf16 for x (and W appended). One 16B-out chunk per thread.
__global__ __launch_bounds__(256)
void cvt_x_w(const float* __restrict__ x, const float* __restrict__ W,
             u32x4* __restrict__ xbf, u32x4* __restrict__ wbf) {
  const int i = blockIdx.x * blockDim.x + threadIdx.x;
  if (i >= XCH + WCH) return;
  const f32x4* src;
  u32x4* dst;
  if (i < XCH) {
    src = reinterpret_cast<const f32x4*>(x) + 2 * (size_t)i;
    dst = xbf + i;
  } else {
    const int k = i - XCH;
    src = reinterpret_cast<const f32x4*>(W) + 2 * (size_t)k;
    dst = wbf + k;
  }
  f32x4 f0 = src[0], f1 = src[1];
  __builtin_nontemporal_store(cvt8(f0, f1), dst);
}

__global__ __launch_bounds__(256)
void cvt_w_only(const float* __restrict__ W, u32x4* __restrict__ wbf) {
  const int i = blockIdx.x * blockDim.x + threadIdx.x;
  if (i < WCH) {
    const f32x4* src = reinterpret_cast<const f32x4*>(W) + 2 * (size_t)i;
    f32x4 f0 = src[0], f1 = src[1];
    wbf[i] = cvt8(f0, f1);
  }
}

// Main gather-GEMM. Block = 1024 threads = 16 waves; each wave owns 16 output
// rows, all 64 out channels. LDS 58KB -> 2 blocks/CU -> 32 waves/CU.
template <int XBF, int WPRE>
__global__ __launch_bounds__(1024, 8)
void gather_mm(const float* __restrict__ x32, const unsigned short* __restrict__ x16,
               const int* __restrict__ neigh,
               const float* __restrict__ W32, const unsigned short* __restrict__ W16,
               const float* __restrict__ bias, float* __restrict__ out) {
  // W in LDS: [o][k], row stride 456 elems (912 B).
  __shared__ __align__(16) unsigned short Wlds[64][456];

  const int tid = threadIdx.x;
  for (int i = tid; i < 64 * 56; i += 1024) {
    const int row = i / 56, ch = i - row * 56;
    u32x4 val;
    if constexpr (WPRE) {
      val = reinterpret_cast<const u32x4*>(W16)[i];
    } else {
      const f32x4* p = reinterpret_cast<const f32x4*>(W32 + row * 448 + ch * 8);
      val = cvt8(p[0], p[1]);
    }
    *reinterpret_cast<u32x4*>(&Wlds[row][ch * 8]) = val;
  }
  __syncthreads();

  const int w    = tid >> 6;      // wave 0..15
  const int lane = tid & 63;
  const int r    = lane & 15;     // A-tile row / out-channel low bits
  const int g    = lane >> 4;     // k-group 0..3
  const int m0   = blockIdx.x * 256 + w * 16;
  if (m0 >= M_TOTAL) return;      // no barriers after this point

  int mA = m0 + r;
  if (mA > M_TOTAL - 1) mA = M_TOTAL - 1;   // clamp for safe index loads
  const int bA = (mA >= V_ICO) ? 1 : 0;
  const int vA = mA - bA * V_ICO;

  int nofs[7];
#pragma unroll
  for (int j = 0; j < 7; ++j) nofs[j] = neigh[vA * 7 + j];

  const unsigned short* xb = nullptr;
  const float* xb32 = nullptr;
  if constexpr (XBF) xb   = x16 + (size_t)bA * V_ICO * 64 + (g << 3);
  else               xb32 = x32 + (size_t)bA * V_ICO * 64 + (g << 3);

  // B-frag base: all 56 LDS reads become base + compile-time imm offset.
  const unsigned short* wp = &Wlds[r][g << 3];

  const f32x4 zero = {0.f, 0.f, 0.f, 0.f};
  f32x4 acc0 = zero, acc1 = zero, acc2 = zero, acc3 = zero;

#define LOAD_J(d0, d1, j) do {                                              \
    if constexpr (XBF) {                                                    \
      const unsigned short* rp = xb + (size_t)nofs[j] * 64;                 \
      d0.q = *reinterpret_cast<const u32x4*>(rp);                           \
      d1.q = *reinterpret_cast<const u32x4*>(rp + 32);                      \
    } else {                                                                \
      const float* rp = xb32 + (size_t)nofs[j] * 64;                        \
      const f32x4* p0 = reinterpret_cast<const f32x4*>(rp);                 \
      const f32x4* p1 = reinterpret_cast<const f32x4*>(rp + 32);            \
      d0.q = cvt8(p0[0], p0[1]);                                            \
      d1.q = cvt8(p1[0], p1[1]);                                            \
    }                                                                       \
  } while (0)

  // COMPUTE: 8 MFMAs for neighbor j (k-chunks kc=2j, 2j+1). Offsets in elems:
  // (16*nt)*456 + kc*32  (g folded into wp).
#define MFMA_NT(afrag, nt, kc)                                              \
    acc##nt = __builtin_amdgcn_mfma_f32_16x16x32_bf16(                      \
        afrag.v,                                                            \
        *reinterpret_cast<const bf16x8*>(wp + (nt) * 16 * 456 + (kc) * 32), \
        acc##nt, 0, 0, 0)

#define COMPUTE_J(d0, d1, j) do {                                           \
    MFMA_NT(d0, 0, 2*(j));   MFMA_NT(d0, 1, 2*(j));                         \
    MFMA_NT(d0, 2, 2*(j));   MFMA_NT(d0, 3, 2*(j));                         \
    MFMA_NT(d1, 0, 2*(j)+1); MFMA_NT(d1, 1, 2*(j)+1);                       \
    MFMA_NT(d1, 2, 2*(j)+1); MFMA_NT(d1, 3, 2*(j)+1);                       \
  } while (0)

  BF8 a0lo, a0hi, a1lo, a1hi;
  LOAD_J(a0lo, a0hi, 0);
  LOAD_J(a1lo, a1hi, 1);
  COMPUTE_J(a0lo, a0hi, 0); LOAD_J(a0lo, a0hi, 2);
  COMPUTE_J(a1lo, a1hi, 1); LOAD_J(a1lo, a1hi, 3);
  COMPUTE_J(a0lo, a0hi, 2); LOAD_J(a0lo, a0hi, 4);
  COMPUTE_J(a1lo, a1hi, 3); LOAD_J(a1lo, a1hi, 5);
  COMPUTE_J(a0lo, a0hi, 4); LOAD_J(a0lo, a0hi, 6);
  COMPUTE_J(a1lo, a1hi, 5);
  COMPUTE_J(a0lo, a0hi, 6);

#undef LOAD_J
#undef MFMA_NT
#undef COMPUTE_J

  // C/D layout: col = lane&15 (= r -> out channel), row = g*4 + reg.
  const float bv0 = bias[r], bv1 = bias[16 + r], bv2 = bias[32 + r], bv3 = bias[48 + r];
#pragma unroll
  for (int q2 = 0; q2 < 4; ++q2) {
    const int mS = m0 + (g << 2) + q2;
    if (mS < M_TOTAL) {
      float* o = out + (size_t)mS * 64;
      __builtin_nontemporal_store(acc0[q2] + bv0, o + r);
      __builtin_nontemporal_store(acc1[q2] + bv1, o + 16 + r);
      __builtin_nontemporal_store(acc2[q2] + bv2, o + 32 + r);
      __builtin_nontemporal_store(acc3[q2] + bv3, o + 48 + r);
    }
  }
}

extern "C" void kernel_launch(void* const* d_in, const int* in_sizes, int n_in,
                              void* d_out, int out_size, void* d_ws, size_t ws_size,
                              hipStream_t stream) {
  const float* x    = (const float*)d_in[0];
  const int*   nbr  = (const int*)d_in[1];
  const float* W    = (const float*)d_in[2];
  const float* bias = (const float*)d_in[3];
  float* out = (float*)d_out;

  const size_t xbf_bytes = (size_t)X_ELEMS * 2;
  const size_t wbf_bytes = (size_t)W_ELEMS * 2;
  const int grid_main = (M_TOTAL + 255) / 256;    // 1281

  if (ws_size >= xbf_bytes + wbf_bytes) {
    u32x4* xbf = (u32x4*)d_ws;
    u32x4* wbf = (u32x4*)((char*)d_ws + xbf_bytes);
    hipLaunchKernelGGL(cvt_x_w, dim3((XCH + WCH + 255) / 256), dim3(256), 0, stream,
                       x, W, xbf, wbf);
    hipLaunchKernelGGL((gather_mm<1, 1>), dim3(grid_main), dim3(1024), 0, stream,
                       x, (const unsigned short*)xbf, nbr,
                       W, (const unsigned short*)wbf, bias, out);
  } else if (ws_size >= wbf_bytes) {
    u32x4* wbf = (u32x4*)d_ws;
    hipLaunchKernelGGL(cvt_w_only, dim3((WCH + 255) / 256), dim3(256), 0, stream, W, wbf);
    hipLaunchKernelGGL((gather_mm<0, 1>), dim3(grid_main), dim3(1024), 0, stream,
                       x, nullptr, nbr, W, (const unsigned short*)wbf, bias, out);
  } else {
    hipLaunchKernelGGL((gather_mm<0, 0>), dim3(grid_main), dim3(1024), 0, stream,
                       x, nullptr, nbr, W, nullptr, bias, out);
  }
}

// Round 3
// 201.472 us; speedup vs baseline: 1.1075x; 1.0304x over previous
//
#include <hip/hip_runtime.h>

// conv_layer: out[b,v,o] = sum_{j<7,c<64} x[b, neigh[v*7+j], c] * W[o, j*64+c] + bias[o]
// B=2, V=163842, C_IN=C_OUT=64, K=448. bf16 MFMA gather-GEMM.
// R3: depth-4 gather pipeline (8 loads in flight), conflict-free fragment-ordered
//     W LDS layout, setprio around MFMA clusters.

constexpr int V_ICO   = 163842;
constexpr int M_TOTAL = 2 * V_ICO;        // 327684
constexpr int X_ELEMS = M_TOTAL * 64;     // 20,971,776
constexpr int W_ELEMS = 64 * 448;         // 28,672
constexpr int XCH     = X_ELEMS / 8;      // 16B bf16 chunks of x
constexpr int WCH     = W_ELEMS / 8;      // 3584

typedef __attribute__((ext_vector_type(4))) float          f32x4;
typedef __attribute__((ext_vector_type(4))) unsigned int   u32x4;
typedef __attribute__((ext_vector_type(8))) unsigned short u16x8;
typedef __attribute__((ext_vector_type(8))) __bf16         bf16x8;

union BF8 { u32x4 q; u16x8 u; bf16x8 v; };

static __device__ __forceinline__ unsigned short f2bf(float f) {
  unsigned int t = __float_as_uint(f);
  t += 0x7FFFu + ((t >> 16) & 1u);   // round-to-nearest-even
  return (unsigned short)(t >> 16);
}

static __device__ __forceinline__ u32x4 cvt8(f32x4 a, f32x4 b) {
  BF8 r;
  r.u[0] = f2bf(a[0]); r.u[1] = f2bf(a[1]); r.u[2] = f2bf(a[2]); r.u[3] = f2bf(a[3]);
  r.u[4] = f2bf(b[0]); r.u[5] = f2bf(b[1]); r.u[6] = f2bf(b[2]); r.u[7] = f2bf(b[3]);
  return r.q;
}

// fp32 -> bf16 for x (and W appended). One 16B-out chunk per thread.
// Normal stores: leave xbf L2-resident for the gather kernel that follows.
__global__ __launch_bounds__(256)
void cvt_x_w(const float* __restrict__ x, const float* __restrict__ W,
             u32x4* __restrict__ xbf, u32x4* __restrict__ wbf) {
  const int i = blockIdx.x * blockDim.x + threadIdx.x;
  if (i >= XCH + WCH) return;
  const f32x4* src;
  u32x4* dst;
  if (i < XCH) {
    src = reinterpret_cast<const f32x4*>(x) + 2 * (size_t)i;
    dst = xbf + i;
  } else {
    const int k = i - XCH;
    src = reinterpret_cast<const f32x4*>(W) + 2 * (size_t)k;
    dst = wbf + k;
  }
  f32x4 f0 = src[0], f1 = src[1];
  *dst = cvt8(f0, f1);
}

__global__ __launch_bounds__(256)
void cvt_w_only(const float* __restrict__ W, u32x4* __restrict__ wbf) {
  const int i = blockIdx.x * blockDim.x + threadIdx.x;
  if (i < WCH) {
    const f32x4* src = reinterpret_cast<const f32x4*>(W) + 2 * (size_t)i;
    f32x4 f0 = src[0], f1 = src[1];
    wbf[i] = cvt8(f0, f1);
  }
}

// Main gather-GEMM. Block = 1024 threads = 16 waves; wave owns 16 output rows,
// all 64 out channels. LDS 57344 B -> 2 blocks/CU -> 32 waves/CU.
// W LDS layout: fragment-ordered Wf[kc][nt][lane][8] so each lane reads its own
// contiguous 16 B (natural 2-way bank aliasing only).
template <int XBF, int WPRE>
__global__ __launch_bounds__(1024, 8)
void gather_mm(const float* __restrict__ x32, const unsigned short* __restrict__ x16,
               const int* __restrict__ neigh,
               const float* __restrict__ W32, const unsigned short* __restrict__ W16,
               const float* __restrict__ bias, float* __restrict__ out) {
  __shared__ __align__(16) unsigned short Wlds[WCH * 8];   // 57344 B

  const int tid  = threadIdx.x;
  const int w    = tid >> 6;      // wave 0..15
  const int lane = tid & 63;
  const int r    = lane & 15;     // A-tile row / out-channel low bits
  const int g    = lane >> 4;     // k-group 0..3
  const int m0   = blockIdx.x * 256 + w * 16;

  int mA = m0 + r;
  if (mA > M_TOTAL - 1) mA = M_TOTAL - 1;   // clamp for safe index loads
  const int bA = (mA >= V_ICO) ? 1 : 0;
  const int vA = mA - bA * V_ICO;

  int nofs[7];
#pragma unroll
  for (int j = 0; j < 7; ++j) nofs[j] = neigh[vA * 7 + j];

  // Stage W, fragment-ordered. dest chunk i = (kc*4+nt)*64 + lane holds
  // W[nt*16 + (lane&15)][kc*32 + (lane>>4)*8 .. +8].
  for (int i = tid; i < WCH; i += 1024) {
    const int kcnt = i >> 6;               // kc*4 + nt
    const int l    = i & 63;
    const int row  = ((kcnt & 3) << 4) | (l & 15);
    u32x4 val;
    if constexpr (WPRE) {
      const int c8 = ((kcnt >> 2) << 2) + (l >> 4);        // col/8
      val = reinterpret_cast<const u32x4*>(W16)[row * 56 + c8];
    } else {
      const int col = ((kcnt >> 2) << 5) + ((l >> 4) << 3);
      const f32x4* p = reinterpret_cast<const f32x4*>(W32 + row * 448 + col);
      val = cvt8(p[0], p[1]);
    }
    *reinterpret_cast<u32x4*>(&Wlds[(size_t)i * 8]) = val;
  }
  __syncthreads();
  if (m0 >= M_TOTAL) return;      // after the only barrier: legal

  const unsigned short* xb = nullptr;
  const float* xb32 = nullptr;
  if constexpr (XBF) xb   = x16 + (size_t)bA * V_ICO * 64 + (g << 3);
  else               xb32 = x32 + (size_t)bA * V_ICO * 64 + (g << 3);

  const unsigned short* wp = Wlds + (lane << 3);   // + (kc*4+nt)*512 imm offsets

  const f32x4 zero = {0.f, 0.f, 0.f, 0.f};
  f32x4 acc0 = zero, acc1 = zero, acc2 = zero, acc3 = zero;

#define MFMA_NT(af, nt, kc)                                                 \
    acc##nt = __builtin_amdgcn_mfma_f32_16x16x32_bf16(                      \
        af.v,                                                               \
        *reinterpret_cast<const bf16x8*>(wp + ((kc) * 4 + (nt)) * 512),     \
        acc##nt, 0, 0, 0)

#define COMPUTE_J(dl, dh, j) do {                                           \
    __builtin_amdgcn_s_setprio(1);                                          \
    MFMA_NT(dl, 0, 2*(j));   MFMA_NT(dl, 1, 2*(j));                         \
    MFMA_NT(dl, 2, 2*(j));   MFMA_NT(dl, 3, 2*(j));                         \
    MFMA_NT(dh, 0, 2*(j)+1); MFMA_NT(dh, 1, 2*(j)+1);                       \
    MFMA_NT(dh, 2, 2*(j)+1); MFMA_NT(dh, 3, 2*(j)+1);                       \
    __builtin_amdgcn_s_setprio(0);                                          \
  } while (0)

  if constexpr (XBF) {
#define LOAD_J(dl, dh, j) do {                                              \
      const unsigned short* rp = xb + (size_t)nofs[j] * 64;                 \
      dl.q = *reinterpret_cast<const u32x4*>(rp);                           \
      dh.q = *reinterpret_cast<const u32x4*>(rp + 32);                      \
    } while (0)

    BF8 b0l, b0h, b1l, b1h, b2l, b2h, b3l, b3h;
    LOAD_J(b0l, b0h, 0);
    LOAD_J(b1l, b1h, 1);
    LOAD_J(b2l, b2h, 2);
    LOAD_J(b3l, b3h, 3);
    COMPUTE_J(b0l, b0h, 0); LOAD_J(b0l, b0h, 4);
    COMPUTE_J(b1l, b1h, 1); LOAD_J(b1l, b1h, 5);
    COMPUTE_J(b2l, b2h, 2); LOAD_J(b2l, b2h, 6);
    COMPUTE_J(b3l, b3h, 3);
    COMPUTE_J(b0l, b0h, 4);
    COMPUTE_J(b1l, b1h, 5);
    COMPUTE_J(b2l, b2h, 6);
#undef LOAD_J
  } else {
    // fp32 fallback (unused when ws fits): simple depth-1 loop.
#pragma unroll
    for (int j = 0; j < 7; ++j) {
      const float* rp = xb32 + (size_t)nofs[j] * 64;
      const f32x4* p0 = reinterpret_cast<const f32x4*>(rp);
      const f32x4* p1 = reinterpret_cast<const f32x4*>(rp + 32);
      BF8 dl, dh;
      dl.q = cvt8(p0[0], p0[1]);
      dh.q = cvt8(p1[0], p1[1]);
      COMPUTE_J(dl, dh, j);
    }
  }
#undef MFMA_NT
#undef COMPUTE_J

  // C/D layout: col = lane&15 (= r -> out channel), row = g*4 + reg.
  const float bv0 = bias[r], bv1 = bias[16 + r], bv2 = bias[32 + r], bv3 = bias[48 + r];
  const bool full = (m0 + 16 <= M_TOTAL);
#pragma unroll
  for (int q2 = 0; q2 < 4; ++q2) {
    const int mS = m0 + (g << 2) + q2;
    if (full || mS < M_TOTAL) {
      float* o = out + (size_t)mS * 64;
      __builtin_nontemporal_store(acc0[q2] + bv0, o + r);
      __builtin_nontemporal_store(acc1[q2] + bv1, o + 16 + r);
      __builtin_nontemporal_store(acc2[q2] + bv2, o + 32 + r);
      __builtin_nontemporal_store(acc3[q2] + bv3, o + 48 + r);
    }
  }
}

extern "C" void kernel_launch(void* const* d_in, const int* in_sizes, int n_in,
                              void* d_out, int out_size, void* d_ws, size_t ws_size,
                              hipStream_t stream) {
  const float* x    = (const float*)d_in[0];
  const int*   nbr  = (const int*)d_in[1];
  const float* W    = (const float*)d_in[2];
  const float* bias = (const float*)d_in[3];
  float* out = (float*)d_out;

  const size_t xbf_bytes = (size_t)X_ELEMS * 2;
  const size_t wbf_bytes = (size_t)W_ELEMS * 2;
  const int grid_main = (M_TOTAL + 255) / 256;    // 1281

  if (ws_size >= xbf_bytes + wbf_bytes) {
    u32x4* xbf = (u32x4*)d_ws;
    u32x4* wbf = (u32x4*)((char*)d_ws + xbf_bytes);
    hipLaunchKernelGGL(cvt_x_w, dim3((XCH + WCH + 255) / 256), dim3(256), 0, stream,
                       x, W, xbf, wbf);
    hipLaunchKernelGGL((gather_mm<1, 1>), dim3(grid_main), dim3(1024), 0, stream,
                       x, (const unsigned short*)xbf, nbr,
                       W, (const unsigned short*)wbf, bias, out);
  } else if (ws_size >= wbf_bytes) {
    u32x4* wbf = (u32x4*)d_ws;
    hipLaunchKernelGGL(cvt_w_only, dim3((WCH + 255) / 256), dim3(256), 0, stream, W, wbf);
    hipLaunchKernelGGL((gather_mm<0, 1>), dim3(grid_main), dim3(1024), 0, stream,
                       x, nullptr, nbr, W, (const unsigned short*)wbf, bias, out);
  } else {
    hipLaunchKernelGGL((gather_mm<0, 0>), dim3(grid_main), dim3(1024), 0, stream,
                       x, nullptr, nbr, W, nullptr, bias, out);
  }
}